// Round 1
// baseline (114.039 us; speedup 1.0000x reference)
//
#include <hip/hip_runtime.h>
#include <hip/hip_bf16.h>

// out[m,n] = sum_k x[m,k] * W[1023-n,k] + b[1023-n]
// M=32768, N=256, K=512; fp32 in/out; bf16 MFMA compute (tolerance 4.3e-2 >> bf16 err ~4e-3)

#define M_TOT 32768
#define K_TOT 512
#define N_TOT 256
#define W_LD  1024

#define BM 128
#define BN 256
#define BK 64
#define NTH 512
#define KSTEPS 8

#define LDS_ABYTES (BM * BK * 2)              /* 16384 */
#define LDS_BUF    (LDS_ABYTES + BN * BK * 2) /* 49152 */

typedef __bf16 bf16x8 __attribute__((ext_vector_type(8)));
typedef float  f32x4  __attribute__((ext_vector_type(4)));

static __device__ __forceinline__ bf16x8 cvt8(f32x4 a, f32x4 b) {
    bf16x8 r;
    r[0] = (__bf16)a[0]; r[1] = (__bf16)a[1]; r[2] = (__bf16)a[2]; r[3] = (__bf16)a[3];
    r[4] = (__bf16)b[0]; r[5] = (__bf16)b[1]; r[6] = (__bf16)b[2]; r[7] = (__bf16)b[3];
    return r;
}

__global__ __launch_bounds__(NTH, 2)
void ng_gemm(const float* __restrict__ x, const float* __restrict__ W,
             const float* __restrict__ bias, float* __restrict__ out)
{
    // double-buffered: [buf0: A 16K | B 32K][buf1: A 16K | B 32K] = 96 KiB
    __shared__ __align__(16) unsigned char lds[2 * LDS_BUF];

    const int tid  = threadIdx.x;
    const int lane = tid & 63;
    const int wid  = tid >> 6;
    const int wr   = wid >> 2;   // 0..1 : wave row (64 rows each)
    const int wc   = wid & 3;    // 0..3 : wave col (64 cols each)
    const long mBase = (long)blockIdx.x * BM;

    // ---- staging geometry: each thread stages 8-float chunks ----
    // A: 128 rows x 64 k  -> 1024 chunks; thread t handles rows (t>>3), (t>>3)+64
    // B: 256 rows x 64 k  -> 2048 chunks; thread t handles n-rows (t>>3)+{0,64,128,192}
    const int srow = tid >> 3;   // 0..63
    const int skg  = tid & 7;    // 8-float chunk within the 64-wide k tile
    const float* srcA = x + (mBase + srow) * K_TOT + skg * 8;
    const float* srcB = W + (long)(1023 - srow) * W_LD + skg * 8;  // reversed rows
    // LDS byte offset within buffer, XOR-swizzled: byte ^= (row&7)<<4
    // (row&7) is invariant under +64 row steps, so one offset serves all units.
    const int swz0 = srow * (BK * 2) + ((skg * 16) ^ ((srow & 7) << 4));

    // ---- compute-side ds_read_b128 byte offsets (per ks-slice, per m/n frag) ----
    int rdA[2][4], rdB[2][4];
#pragma unroll
    for (int ks = 0; ks < 2; ++ks) {
        const int col = ks * 64 + (lane >> 4) * 16;  // 16B k-group per lane quad
#pragma unroll
        for (int i = 0; i < 4; ++i) {
            const int ra = wr * 64 + i * 16 + (lane & 15);
            const int rb = wc * 64 + i * 16 + (lane & 15);
            rdA[ks][i] = ra * (BK * 2) + (col ^ ((ra & 7) << 4));
            rdB[ks][i] = LDS_ABYTES + rb * (BK * 2) + (col ^ ((rb & 7) << 4));
        }
    }

    f32x4 acc[4][4];
#pragma unroll
    for (int mi = 0; mi < 4; ++mi)
#pragma unroll
        for (int ni = 0; ni < 4; ++ni)
            acc[mi][ni] = (f32x4){0.f, 0.f, 0.f, 0.f};

    f32x4 rgA[2][2], rgB[4][2];

#define LOADT(kt_) do {                                                   \
        const float* pa_ = srcA + (kt_) * BK;                             \
        rgA[0][0] = *(const f32x4*)(pa_);                                 \
        rgA[0][1] = *(const f32x4*)(pa_ + 4);                             \
        rgA[1][0] = *(const f32x4*)(pa_ + 64 * K_TOT);                    \
        rgA[1][1] = *(const f32x4*)(pa_ + 64 * K_TOT + 4);                \
        const float* pb_ = srcB + (kt_) * BK;                             \
        rgB[0][0] = *(const f32x4*)(pb_);                                 \
        rgB[0][1] = *(const f32x4*)(pb_ + 4);                             \
        rgB[1][0] = *(const f32x4*)(pb_ - 64 * W_LD);                     \
        rgB[1][1] = *(const f32x4*)(pb_ - 64 * W_LD + 4);                 \
        rgB[2][0] = *(const f32x4*)(pb_ - 128 * W_LD);                    \
        rgB[2][1] = *(const f32x4*)(pb_ - 128 * W_LD + 4);                \
        rgB[3][0] = *(const f32x4*)(pb_ - 192 * W_LD);                    \
        rgB[3][1] = *(const f32x4*)(pb_ - 192 * W_LD + 4);                \
    } while (0)

#define WRITET(base_) do {                                                              \
        *(bf16x8*)(lds + (base_) + swz0)                         = cvt8(rgA[0][0], rgA[0][1]); \
        *(bf16x8*)(lds + (base_) + swz0 + 64 * 128)              = cvt8(rgA[1][0], rgA[1][1]); \
        *(bf16x8*)(lds + (base_) + LDS_ABYTES + swz0)            = cvt8(rgB[0][0], rgB[0][1]); \
        *(bf16x8*)(lds + (base_) + LDS_ABYTES + swz0 + 1 * 8192) = cvt8(rgB[1][0], rgB[1][1]); \
        *(bf16x8*)(lds + (base_) + LDS_ABYTES + swz0 + 2 * 8192) = cvt8(rgB[2][0], rgB[2][1]); \
        *(bf16x8*)(lds + (base_) + LDS_ABYTES + swz0 + 3 * 8192) = cvt8(rgB[3][0], rgB[3][1]); \
    } while (0)

#define COMPUTET(base_) do {                                                    \
        _Pragma("unroll")                                                       \
        for (int ks_ = 0; ks_ < 2; ++ks_) {                                     \
            bf16x8 af_[4], bf_[4];                                              \
            _Pragma("unroll")                                                   \
            for (int i_ = 0; i_ < 4; ++i_) {                                    \
                af_[i_] = *(const bf16x8*)(lds + (base_) + rdA[ks_][i_]);       \
                bf_[i_] = *(const bf16x8*)(lds + (base_) + rdB[ks_][i_]);       \
            }                                                                   \
            _Pragma("unroll")                                                   \
            for (int mi_ = 0; mi_ < 4; ++mi_)                                   \
                _Pragma("unroll")                                               \
                for (int ni_ = 0; ni_ < 4; ++ni_)                               \
                    acc[mi_][ni_] = __builtin_amdgcn_mfma_f32_16x16x32_bf16(    \
                        af_[mi_], bf_[ni_], acc[mi_][ni_], 0, 0, 0);            \
        }                                                                       \
    } while (0)

    // prologue: stage tile 0
    LOADT(0);
    WRITET(0);
    __syncthreads();

    // main loop: issue next-tile loads EARLY (T14), compute current, write next, one barrier
#pragma unroll
    for (int t = 0; t < KSTEPS; ++t) {
        const int cur = (t & 1) * LDS_BUF;
        const int nxt = LDS_BUF - cur;
        if (t + 1 < KSTEPS) LOADT(t + 1);
        COMPUTET(cur);
        if (t + 1 < KSTEPS) WRITET(nxt);
        __syncthreads();
    }

    // ---- epilogue: C/D layout col=lane&15, row=(lane>>4)*4+i ; add reversed bias ----
    const int cRow = wr * 64 + (lane >> 4) * 4;
    const int cCol = wc * 64 + (lane & 15);
#pragma unroll
    for (int ni = 0; ni < 4; ++ni) {
        const int gn = cCol + ni * 16;
        const float bv = bias[1023 - gn];
#pragma unroll
        for (int mi = 0; mi < 4; ++mi) {
            float* dst = out + (mBase + cRow + mi * 16) * (long)N_TOT + gn;
#pragma unroll
            for (int i = 0; i < 4; ++i)
                dst[(long)i * N_TOT] = acc[mi][ni][i] + bv;
        }
    }
#undef LOADT
#undef WRITET
#undef COMPUTET
}

extern "C" void kernel_launch(void* const* d_in, const int* in_sizes, int n_in,
                              void* d_out, int out_size, void* d_ws, size_t ws_size,
                              hipStream_t stream) {
    const float* x = (const float*)d_in[0];   // 32768 x 512 fp32
    const float* W = (const float*)d_in[1];   // 1024 x 1024 fp32
    const float* b = (const float*)d_in[2];   // 1024 fp32
    float* out = (float*)d_out;               // 32768 x 256 fp32
    ng_gemm<<<dim3(M_TOT / BM), dim3(NTH), 0, stream>>>(x, W, b, out);
}

// Round 3
// 113.353 us; speedup vs baseline: 1.0061x; 1.0061x over previous
//
#include <hip/hip_runtime.h>
#include <hip/hip_bf16.h>

// out[m,n] = sum_k x[m,k] * W[1023-n,k] + b[1023-n]
// M=32768, N=256, K=512; fp32 in/out; bf16 MFMA compute.
// Two kernels: (1) prepass converts W_sel -> bf16 swizzled per-K-step LDS images in d_ws;
//              (2) GEMM stages B via global_load_lds (zero VGPR/cvt cost), A via reg+cvt.

#define M_TOT 32768
#define K_TOT 512
#define N_TOT 256
#define W_LD  1024

#define BM 64
#define BK 64
#define NTH 512
#define KSTEPS 8

#define A_BYTES (BM * BK * 2)        /* 8192  */
#define B_BYTES (N_TOT * BK * 2)     /* 32768 */
#define LDS_BUF (A_BYTES + B_BYTES)  /* 40960; x2 buffers = 80 KiB -> 2 blocks/CU */

typedef __bf16 bf16x8 __attribute__((ext_vector_type(8)));
typedef float  f32x4  __attribute__((ext_vector_type(4)));

static __device__ __forceinline__ bf16x8 cvt8(f32x4 a, f32x4 b) {
    bf16x8 r;
    r[0] = (__bf16)a[0]; r[1] = (__bf16)a[1]; r[2] = (__bf16)a[2]; r[3] = (__bf16)a[3];
    r[4] = (__bf16)b[0]; r[5] = (__bf16)b[1]; r[6] = (__bf16)b[2]; r[7] = (__bf16)b[3];
    return r;
}

// ---- prepass: W (fp32, reversed rows) -> bf16 swizzled K-step images ----
// image[kt] is the exact 32 KiB LDS byte image the GEMM wants for K-step kt:
//   row r (= n index), element k at byte  r*128 + ((k*2) ^ ((r&7)<<4))
__global__ __launch_bounds__(256)
void ng_prep(const float* __restrict__ W, unsigned char* __restrict__ img)
{
    const int id = blockIdx.x * 256 + threadIdx.x;  // 16384 units: kt(8) x r(256) x c(8)
    const int kt = id >> 11;
    const int r  = (id >> 3) & 255;
    const int c  = id & 7;
    const float* src = W + (long)(1023 - r) * W_LD + kt * 64 + c * 8;
    f32x4 a = *(const f32x4*)src;
    f32x4 b = *(const f32x4*)(src + 4);
    *(bf16x8*)(img + kt * B_BYTES + r * 128 + ((c * 16) ^ ((r & 7) << 4))) = cvt8(a, b);
}

#define GLL16(gp_, lp_) __builtin_amdgcn_global_load_lds(                     \
        (const __attribute__((address_space(1))) void*)(gp_),                 \
        (__attribute__((address_space(3))) void*)(lp_), 16, 0, 0)

__global__ __launch_bounds__(NTH, 4)
void ng_gemm(const float* __restrict__ x, const unsigned char* __restrict__ wimg,
             const float* __restrict__ bias, float* __restrict__ out)
{
    __shared__ __align__(16) unsigned char lds[2 * LDS_BUF];

    const int tid  = threadIdx.x;
    const int lane = tid & 63;
    const int wid  = tid >> 6;
    const int wrow = wid >> 2;   // 0..1 : 32 output rows each
    const int wcol = wid & 3;    // 0..3 : 64 output cols each
    const long mBase = (long)blockIdx.x * BM;

    // ---- A staging: 64 rows x 8 chunks = 512 units, exactly 1 per thread ----
    const int arow = tid >> 3;   // 0..63
    const int skg  = tid & 7;    // 8-float chunk in k
    const float* srcA = x + (mBase + arow) * K_TOT + skg * 8;
    const int swzA = arow * 128 + ((skg * 16) ^ ((arow & 7) << 4));

    // ---- compute-side ds_read_b128 offsets ----
    int rdA[2][2], rdB[2][4];
#pragma unroll
    for (int ks = 0; ks < 2; ++ks) {
        const int col = ks * 64 + (lane >> 4) * 16;
#pragma unroll
        for (int i = 0; i < 2; ++i) {
            const int ra = wrow * 32 + i * 16 + (lane & 15);
            rdA[ks][i] = ra * 128 + (col ^ ((ra & 7) << 4));
        }
#pragma unroll
        for (int j = 0; j < 4; ++j) {
            const int rb = wcol * 64 + j * 16 + (lane & 15);
            rdB[ks][j] = A_BYTES + rb * 128 + (col ^ ((rb & 7) << 4));
        }
    }

    f32x4 acc[2][4];
#pragma unroll
    for (int mi = 0; mi < 2; ++mi)
#pragma unroll
        for (int ni = 0; ni < 4; ++ni)
            acc[mi][ni] = (f32x4){0.f, 0.f, 0.f, 0.f};

    f32x4 rgA0, rgA1;

#define STAGEB(kt_, base_) do {                                               \
        const unsigned char* s_ = wimg + (kt_) * B_BYTES;                     \
        _Pragma("unroll")                                                     \
        for (int c_ = 0; c_ < 4; ++c_)                                        \
            GLL16(s_ + c_ * 8192 + tid * 16,                                  \
                  lds + (base_) + A_BYTES + c_ * 8192 + wid * 1024);          \
    } while (0)

#define LOADA(kt_) do {                                                       \
        const float* p_ = srcA + (kt_) * BK;                                  \
        rgA0 = *(const f32x4*)(p_);                                           \
        rgA1 = *(const f32x4*)(p_ + 4);                                       \
    } while (0)

#define WRITEA(base_) do {                                                    \
        *(bf16x8*)(lds + (base_) + swzA) = cvt8(rgA0, rgA1);                  \
    } while (0)

#define COMPUTET(base_) do {                                                  \
        _Pragma("unroll")                                                     \
        for (int ks_ = 0; ks_ < 2; ++ks_) {                                   \
            bf16x8 af_[2], bf_[4];                                            \
            _Pragma("unroll")                                                 \
            for (int i_ = 0; i_ < 2; ++i_)                                    \
                af_[i_] = *(const bf16x8*)(lds + (base_) + rdA[ks_][i_]);     \
            _Pragma("unroll")                                                 \
            for (int j_ = 0; j_ < 4; ++j_)                                    \
                bf_[j_] = *(const bf16x8*)(lds + (base_) + rdB[ks_][j_]);     \
            _Pragma("unroll")                                                 \
            for (int mi_ = 0; mi_ < 2; ++mi_)                                 \
                _Pragma("unroll")                                             \
                for (int ni_ = 0; ni_ < 4; ++ni_)                             \
                    acc[mi_][ni_] = __builtin_amdgcn_mfma_f32_16x16x32_bf16(  \
                        af_[mi_], bf_[ni_], acc[mi_][ni_], 0, 0, 0);          \
        }                                                                     \
    } while (0)

    // prologue: stage tile 0
    STAGEB(0, 0);
    LOADA(0);
    WRITEA(0);
    __syncthreads();

#pragma unroll
    for (int t = 0; t < KSTEPS; ++t) {
        const int cur = (t & 1) * LDS_BUF;
        const int nxt = LDS_BUF - cur;
        if (t + 1 < KSTEPS) {
            STAGEB(t + 1, nxt);   // async global->LDS, in flight across compute
            LOADA(t + 1);         // A regs, consumed by WRITEA below
        }
        COMPUTET(cur);
        if (t + 1 < KSTEPS) WRITEA(nxt);
        __syncthreads();
    }

    // ---- epilogue: C/D layout col=lane&15, row=(lane>>4)*4+i ; reversed bias ----
    const int cRow = wrow * 32 + (lane >> 4) * 4;
    const int cCol = wcol * 64 + (lane & 15);
#pragma unroll
    for (int ni = 0; ni < 4; ++ni) {
        const int gn = cCol + ni * 16;
        const float bv = bias[1023 - gn];
#pragma unroll
        for (int mi = 0; mi < 2; ++mi) {
            float* dst = out + (mBase + cRow + mi * 16) * (long)N_TOT + gn;
#pragma unroll
            for (int i = 0; i < 4; ++i)
                dst[(long)i * N_TOT] = acc[mi][ni][i] + bv;
        }
    }
#undef STAGEB
#undef LOADA
#undef WRITEA
#undef COMPUTET
}

extern "C" void kernel_launch(void* const* d_in, const int* in_sizes, int n_in,
                              void* d_out, int out_size, void* d_ws, size_t ws_size,
                              hipStream_t stream) {
    const float* x = (const float*)d_in[0];   // 32768 x 512 fp32
    const float* W = (const float*)d_in[1];   // 1024 x 1024 fp32
    const float* b = (const float*)d_in[2];   // 1024 fp32
    float* out = (float*)d_out;               // 32768 x 256 fp32
    unsigned char* img = (unsigned char*)d_ws; // 256 KiB bf16 swizzled W images

    ng_prep<<<dim3(64), dim3(256), 0, stream>>>(W, img);
    ng_gemm<<<dim3(M_TOT / BM), dim3(NTH), 0, stream>>>(x, img, b, out);
}